// Round 14
// baseline (116.255 us; speedup 1.0000x reference)
//
#include <hip/hip_runtime.h>

typedef __attribute__((ext_vector_type(4))) float f32x4;
typedef __attribute__((ext_vector_type(8))) short short8;

#define EPSF 1e-12f

__device__ __forceinline__ ushort bf16rne(float x) {
  uint u = __float_as_uint(x);
  u += 0x7fffu + ((u >> 16) & 1u);
  return (ushort)(u >> 16);
}
__device__ __forceinline__ float bf2f(ushort h) {
  return __uint_as_float(((uint)h) << 16);
}
__device__ __forceinline__ f32x4 mfma16(short8 a, short8 b, f32x4 c) {
  return __builtin_amdgcn_mfma_f32_16x16x32_bf16(a, b, c, 0, 0, 0);
}

// ---------------------------------------------------------------------------
// K0: W [512][64] f32 -> fragment-major W^T bf16 hi/lo (unchanged).
// ---------------------------------------------------------------------------
__global__ __launch_bounds__(256) void k0_wt(const float* __restrict__ W,
                                             ushort* __restrict__ ws2) {
  int k = blockIdx.x;  // 64
  int mi = k >> 4, l15k = k & 15;
  for (int task = threadIdx.x; task < 512; task += 256) {
    int dg8 = task >> 3, j = task & 7;
    int d = dg8 * 8 + j;
    int s2 = dg8 >> 2, hi16d = dg8 & 3;
    int l = hi16d * 16 + l15k;
    float v = W[(size_t)d * 64 + k];
    ushort h = bf16rne(v);
    size_t idx = ((size_t)(s2 * 4 + mi) * 64 + l) * 8 + j;
    ws2[idx] = h;
    ws2[32768 + idx] = bf16rne(v - bf2f(h));
  }
}

// ---------------------------------------------------------------------------
// K1 (cell kernel, R12 structure + two fixes):
//  * LDS x-image row stride 524 u16 (8*1048 mod 128 = 64 -> pr/pr+8 split;
//    bank map for pr=0..11 all-distinct; junk lanes pr=l15-12, 2-way free)
//  * a^T dumped COALESCED: stage a into 3KB LDS [plane][k][12]u16, then 192
//    float4 stores into cell-contiguous ws layout [region][row][plane][k][12]
// ---------------------------------------------------------------------------
__global__ __launch_bounds__(256, 6) void k1_assign(
    const float* __restrict__ x, const ushort* __restrict__ ws2,
    ushort* __restrict__ aTu, float* __restrict__ asum_ws) {
  __shared__ char sm[25664];
  ushort* xH = (ushort*)sm;               // [12 p][524 u16]
  ushort* xL = (ushort*)(sm + 12576);
  ushort* aStage = (ushort*)sm;           // overlay: [2 plane][64 k][12 p] u16
  float* smax = (float*)(sm + 25152);     // [4 w][16 p]
  float* ssum = (float*)(sm + 25408);

  int b = blockIdx.x;  // 3456 = 32 n * 36 y * 3 col
  int n = b / 108, rem = b % 108;
  int y = rem / 3, col = rem % 3;
  int t = threadIdx.x;
  int w = t >> 6, lane = t & 63, l15 = lane & 15, hi16 = lane >> 4;
  const float4* xb4 =
      (const float4*)(x + ((size_t)n * 1296 + y * 36 + col * 12) * 512);

  // ---- stage: 1536 f4 tasks, 6 per thread, all independent ----
  float4 stg[6];
#pragma unroll
  for (int i = 0; i < 6; ++i) stg[i] = xb4[t + i * 256];
#pragma unroll
  for (int i = 0; i < 6; ++i) {
    int idx = t + i * 256;
    int p = idx >> 7, q = idx & 127;
    int gp = (q >> 1) ^ (p & 7);
    int off = p * 524 + gp * 8 + (q & 1) * 4;
    float4 v = stg[i];
    ushort h0 = bf16rne(v.x), h1 = bf16rne(v.y), h2 = bf16rne(v.z), h3 = bf16rne(v.w);
    uint2 hp, lp;
    hp.x = (uint)h0 | ((uint)h1 << 16);
    hp.y = (uint)h2 | ((uint)h3 << 16);
    lp.x = (uint)bf16rne(v.x - bf2f(h0)) | ((uint)bf16rne(v.y - bf2f(h1)) << 16);
    lp.y = (uint)bf16rne(v.z - bf2f(h2)) | ((uint)bf16rne(v.w - bf2f(h3)) << 16);
    *(uint2*)(xH + off) = hp;
    *(uint2*)(xL + off) = lp;
  }
  __syncthreads();   // staging barrier

  // ---- 16 MFMA steps, barrier-free ----
  int pr = (l15 < 12) ? l15 : (l15 - 12);   // junk cols alias rows 0..3 (2-way)
  f32x4 acc = (f32x4){0.f, 0.f, 0.f, 0.f};
#pragma unroll
  for (int s = 0; s < 16; ++s) {
    const ushort* aPtr = ws2 + ((size_t)(s * 4 + w) * 64 + lane) * 8;
    short8 aH = *(const short8*)aPtr;
    short8 aL = *(const short8*)(aPtr + 32768);
    int g = s * 4 + hi16;
    const ushort* bp = xH + pr * 524 + ((g ^ (pr & 7)) << 3);
    short8 bH = *(const short8*)bp;
    short8 bL = *(const short8*)(bp + 12576 / 2);
    acc = mfma16(aH, bH, acc);
    acc = mfma16(aH, bL, acc);
    acc = mfma16(aL, bH, acc);
  }

  // ---- softmax over k (wave w holds k = w*16 + hi16*4 + rr; col p = l15) ----
  {
    float m = fmaxf(fmaxf(acc[0], acc[1]), fmaxf(acc[2], acc[3]));
    m = fmaxf(m, __shfl_xor(m, 16));
    m = fmaxf(m, __shfl_xor(m, 32));
    if (hi16 == 0) smax[w * 16 + l15] = m;
  }
  __syncthreads();   // also: all MFMA xH reads complete
  float e[4];
  {
    float M = fmaxf(fmaxf(smax[0 * 16 + l15], smax[1 * 16 + l15]),
                    fmaxf(smax[2 * 16 + l15], smax[3 * 16 + l15]));
    float s = 0.f;
#pragma unroll
    for (int rr = 0; rr < 4; ++rr) {
      e[rr] = __expf(acc[rr] - M);
      s += e[rr];
    }
    s += __shfl_xor(s, 16);
    s += __shfl_xor(s, 32);
    if (hi16 == 0) ssum[w * 16 + l15] = s;
  }
  __syncthreads();
  float S = ssum[0 * 16 + l15] + ssum[1 * 16 + l15] + ssum[2 * 16 + l15] +
            ssum[3 * 16 + l15];
  float inv = 1.f / S;

  // ---- a values: asum reduce + stage into LDS [plane][k][12] ----
#pragma unroll
  for (int rr = 0; rr < 4; ++rr) {
    float a = (l15 < 12) ? e[rr] * inv : 0.f;
    int k = w * 16 + hi16 * 4 + rr;
    float s = a;
    s += __shfl_xor(s, 1);
    s += __shfl_xor(s, 2);
    s += __shfl_xor(s, 4);
    s += __shfl_xor(s, 8);
    if (l15 == 0) asum_ws[(size_t)b * 64 + k] = s;
    if (l15 < 12) {
      ushort h = bf16rne(a);
      aStage[k * 12 + l15] = h;                 // plane 0 (hi)
      aStage[768 + k * 12 + l15] = bf16rne(a - bf2f(h));  // plane 1 (lo)
    }
  }
  __syncthreads();   // aStage visible

  // ---- coalesced dump: cell slot = 3072 B contiguous ----
  // ws layout: region*36864 + row*3072 + (plane*1536 + k*24 + p*2)
  if (t < 192) {
    float4 v = ((const float4*)aStage)[t];
    float4* dst = (float4*)(aTu + (size_t)(n * 9 + (y / 12) * 3 + col) * 18432 +
                            (size_t)(y % 12) * 1536);
    dst[t] = v;
  }
}

// ---------------------------------------------------------------------------
// K2: per (n,r,dc of 64): V = X^T * A - C*asum.
// Copy phase now REARRANGES the cell-contiguous aT (linear uint2 reads ->
// [k][152] LDS image writes) + zero-pads cols 144..151. MFMA etc unchanged.
// ---------------------------------------------------------------------------
__global__ __launch_bounds__(512, 8) void k2_vlad(
    const float* __restrict__ x, const float* __restrict__ C,
    const ushort* __restrict__ aTu, const float* __restrict__ asum_ws,
    float* __restrict__ out, float* __restrict__ colnorm) {
  __shared__ float4 smv[2504];               // 40064 B
  char* sm = (char*)smv;
  ushort* atH = (ushort*)sm;                 // [64 k][152 p]
  ushort* atL = (ushort*)(sm + 19456);
  int* poff = (int*)(sm + 38912);            // [160]
  float* asumS = (float*)(sm + 39552);
  float* cn2 = (float*)(sm + 39808);

  int b = blockIdx.x;          // 2304
  int reg = b % 288;
  int dc = b / 288;
  int n = reg / 9, r = reg % 9;
  int d0 = dc * 64;
  int y1 = (r / 3) * 12, x1 = (r % 3) * 12;
  int t = threadIdx.x;
  int w = t >> 6, lane = t & 63, l15 = lane & 15, hi16 = lane >> 4;
  const float* xn = x + (size_t)n * (36 * 36 * 512);

  if (t < 160) poff[t] = (t < 144) ? ((y1 + t / 12) * 36 + (x1 + t % 12)) * 512 : 0;
  if (t < 64) {
    int ry = r / 3, rc = r % 3;
    float s = 0.f;
#pragma unroll
    for (int j = 0; j < 12; ++j)
      s += asum_ws[(size_t)(n * 108 + (ry * 12 + j) * 3 + rc) * 64 + t];
    asumS[t] = s;
    cn2[t] = 0.f;
  }
  // rearranging copy: region = 4608 contiguous uint2; LDS [k][152] image
  {
    const uint2* src = (const uint2*)(aTu + (size_t)reg * 18432);
#pragma unroll
    for (int i = 0; i < 9; ++i) {
      int tau = t + i * 512;
      uint2 v = src[tau];
      int row = tau / 384;
      int rm = tau - row * 384;
      int plane = rm / 192;
      int rm2 = rm - plane * 192;
      int k = rm2 / 3, c = rm2 - k * 3;
      *(uint2*)(sm + plane * 19456 + k * 304 + row * 24 + c * 8) = v;
    }
    if (t < 256) {  // zero-pad u16 cols 144..151
      int plane = t >> 7, k = (t >> 1) & 63, h = t & 1;
      uint2 z; z.x = 0u; z.y = 0u;
      *(uint2*)(sm + plane * 19456 + k * 304 + 288 + h * 8) = z;
    }
  }
  __syncthreads();

  int mi = w & 3, kh = w >> 2;
  int drow = d0 + mi * 16 + l15;
  const float* xcol = xn + drow;

  f32x4 acc[2];
  acc[0] = (f32x4){0.f, 0.f, 0.f, 0.f};
  acc[1] = (f32x4){0.f, 0.f, 0.f, 0.f};

#pragma unroll
  for (int ks = 0; ks < 5; ++ks) {
    int pb = ks * 32 + hi16 * 8;
    int4 poA = *reinterpret_cast<const int4*>(&poff[pb]);
    int4 poB = *reinterpret_cast<const int4*>(&poff[pb + 4]);
    float av[8];
    av[0] = xcol[poA.x]; av[1] = xcol[poA.y];
    av[2] = xcol[poA.z]; av[3] = xcol[poA.w];
    av[4] = xcol[poB.x]; av[5] = xcol[poB.y];
    av[6] = xcol[poB.z]; av[7] = xcol[poB.w];
    bool valid = (ks < 4) || (hi16 < 2);
    short8 ah, al;
#pragma unroll
    for (int j = 0; j < 8; ++j) {
      float v = valid ? av[j] : 0.f;
      ushort h = bf16rne(v);
      ah[j] = (short)h;
      al[j] = (short)bf16rne(v - bf2f(h));
    }
#pragma unroll
    for (int ni = 0; ni < 2; ++ni) {
      int row = kh * 32 + ni * 16 + l15;
      short8 bh = *(const short8*)(atH + row * 152 + pb);
      short8 bl = *(const short8*)(atL + row * 152 + pb);
      f32x4 a0 = acc[ni];
      a0 = mfma16(ah, bh, a0);
      a0 = mfma16(ah, bl, a0);
      a0 = mfma16(al, bh, a0);
      acc[ni] = a0;
    }
  }

  size_t obase = (size_t)reg * (512 * 64);
#pragma unroll
  for (int ni = 0; ni < 2; ++ni) {
    int k = kh * 32 + ni * 16 + l15;
    float ak = asumS[k];
    float s2 = 0.f;
#pragma unroll
    for (int rr = 0; rr < 4; ++rr) {
      int d = d0 + mi * 16 + hi16 * 4 + rr;
      float v = acc[ni][rr] - C[(size_t)d * 64 + k] * ak;
      out[obase + (size_t)d * 64 + k] = v;
      s2 += v * v;
    }
    atomicAdd(&cn2[k], s2);
  }
  __syncthreads();
  if (t < 64) colnorm[(size_t)(reg * 8 + dc) * 64 + t] = cn2[t];
}

// ---------------------------------------------------------------------------
// K3: intra-norm + global-norm scaling in place (sums 8 partial colnorms).
// ---------------------------------------------------------------------------
__global__ __launch_bounds__(256) void k3_scale(float* __restrict__ out,
                                                const float* __restrict__ colnorm) {
  int b = blockIdx.x;  // 1152
  int reg = b % 288;
  int dc = b / 288;

  __shared__ float ratio[64];
  __shared__ float fs[64];
  int t = threadIdx.x;
  float c = 0.f;
  if (t < 64) {
#pragma unroll
    for (int j = 0; j < 8; ++j) c += colnorm[(size_t)(reg * 8 + j) * 64 + t];
    ratio[t] = c / (c + EPSF);
  }
  __syncthreads();
  if (t < 64) {
    float g = 0.f;
#pragma unroll
    for (int j = 0; j < 64; ++j) g += ratio[j];
    fs[t] = rsqrtf(c + EPSF) * rsqrtf(g + EPSF);
  }
  __syncthreads();

  size_t base4 = (((size_t)reg * 512) + (size_t)dc * 128) * 64 / 4;
  float4* o4 = reinterpret_cast<float4*>(out);
  for (int j = 0; j < 8; ++j) {
    size_t idx = base4 + t + 256 * j;
    float4 v = o4[idx];
    int k0 = (int)((idx * 4) & 63);
    v.x *= fs[k0]; v.y *= fs[k0 + 1]; v.z *= fs[k0 + 2]; v.w *= fs[k0 + 3];
    o4[idx] = v;
  }
}

extern "C" void kernel_launch(void* const* d_in, const int* in_sizes, int n_in,
                              void* d_out, int out_size, void* d_ws, size_t ws_size,
                              hipStream_t stream) {
  const float* x = (const float*)d_in[0];   // [32,36,36,512]
  const float* Wc = (const float*)d_in[1];  // [512,64]
  const float* C = (const float*)d_in[2];   // [512,64]
  float* out = (float*)d_out;

  char* ws = (char*)d_ws;
  ushort* ws2 = (ushort*)(ws);              // 131072 B
  float* asum_ws = (float*)(ws + 131072);   // 3456*64*4 = 884736 B
  float* colnorm = (float*)(ws + 1015808);  // 2304*64*4 = 589824 B
  char* aT_base = ws + 1605632;             // 288 * 36864 B = 10.6 MB

  k0_wt<<<64, 256, 0, stream>>>(Wc, ws2);
  k1_assign<<<3456, 256, 0, stream>>>(x, ws2, (ushort*)aT_base, asum_ws);
  k2_vlad<<<2304, 512, 0, stream>>>(x, C, (const ushort*)aT_base, asum_ws, out, colnorm);
  k3_scale<<<1152, 256, 0, stream>>>(out, colnorm);
}